// Round 25
// baseline (225.449 us; speedup 1.0000x reference)
//
#include <hip/hip_runtime.h>
#include <stdint.h>

#define SEQ_LEN 131072
#define IN_DIM  8
#define HID     50
#define NLAYERS 5
#define CHUNK2  256                  // outputs per CHAIN; 2 chains per block (waves 0-5 / 6-11)
#define WARMUP  48                   // locked (R22)
#define NBLOCKS (SEQ_LEN / (2 * CHUNK2))  // 256 blocks == 256 CUs
#define RING    64
#define RSH     64                   // halves per ring row: 128B; k=50..63 stay ZERO (MFMA K-pad)
#define XT      64                   // x-tile steps (double buffered); win=304 -> partial last tile
#define G       4                    // R25: sync group 8->4 (fill skew 40->20 slots). MFMA tile stays
                                     // 16 cols; cols G..15 garbage, never consumed.
#define GP      16                   // PRE buffer rows == MFMA N-tile (unchanged)

typedef float    v4f   __attribute__((ext_vector_type(4)));
typedef float    f32x4 __attribute__((ext_vector_type(4)));
typedef _Float16 h2    __attribute__((ext_vector_type(2)));
typedef _Float16 h8    __attribute__((ext_vector_type(8)));

#if __has_builtin(__builtin_amdgcn_fdot2)
#define FDOT2(a, b, c) __builtin_amdgcn_fdot2((a), (b), (c), false)
#else
#define FDOT2(a, b, c) __builtin_fmaf((float)(a).x, (float)(b).x, \
                        __builtin_fmaf((float)(a).y, (float)(b).y, (c)))
#endif

__device__ __forceinline__ float fast_tanh(float x) {
    float e = __expf(2.0f * x);
    return 1.0f - 2.0f * __builtin_amdgcn_rcpf(1.0f + e);
}
__device__ __forceinline__ float fast_sigmoid(float x) {
    float e = __expf(-x);
    return __builtin_amdgcn_rcpf(1.0f + e);
}
__device__ __forceinline__ void wait_ge(volatile int* p, int target) {
    while (__hip_atomic_load((int*)p, __ATOMIC_ACQUIRE, __HIP_MEMORY_SCOPE_WORKGROUP) < target) {}
}
// 7 x ds_read_b128 wave-uniform broadcast of one f16 h-row (112B used of 128B)
__device__ __forceinline__ void load7(h8* v, const _Float16* p) {
    const h8* p8 = (const h8*)p;
#pragma unroll
    for (int q = 0; q < 7; q++) v[q] = p8[q];
}
// 50 f32 weights -> 28 h2 (f16), zero-padded
__device__ __forceinline__ void loadw_h(const float* wp, h2* v) {
#pragma unroll
    for (int i = 0; i < 25; i++)
        v[i] = h2{(_Float16)wp[2*i], (_Float16)wp[2*i+1]};
    v[25] = h2{(_Float16)0.f, (_Float16)0.f};
    v[26] = h2{(_Float16)0.f, (_Float16)0.f};
    v[27] = h2{(_Float16)0.f, (_Float16)0.f};
}
// acc += a(56 halves) . w(28 h2), f32 accumulate via v_dot2_f32_f16, 4 chains
__device__ __forceinline__ void dot28(const h8* a, const h2* w,
                                      float& A, float& B, float& C, float& D) {
#pragma unroll
    for (int q = 0; q < 7; q++) {
        A = FDOT2(__builtin_shufflevector(a[q], a[q], 0, 1), w[4*q+0], A);
        B = FDOT2(__builtin_shufflevector(a[q], a[q], 2, 3), w[4*q+1], B);
        C = FDOT2(__builtin_shufflevector(a[q], a[q], 4, 5), w[4*q+2], C);
        D = FDOT2(__builtin_shufflevector(a[q], a[q], 6, 7), w[4*q+3], D);
    }
}

// Layers 1..4 (runtime L: one I-stream shared by 8 waves across both chains).
// hin contribution = bulk MFMA GEMM, 16-col tile, only cols [0,G) consumed.
// hse recurrence serial in LDS at prio 1 (T5); release store INSIDE the prio-1
// region (R25): the prog[L] store is the consumer's critical path.
__device__ void layer_mfma(
    _Float16 (&ring)[NLAYERS][RING][RSH],
    float (&pre_lds)[NLAYERS - 1][GP][68],
    int* prog, const int L,
    const float* __restrict__ WihR, const float* __restrict__ Whh,
    const float* __restrict__ bih,  const float* __restrict__ bhh,
    const int lane, const int win)
{
    const int j = (lane < HID) ? lane : 0;
    h2 whhv[28];
    loadw_h(Whh + (size_t)L * HID * HID + j * HID, whhv);
    const float bias = bih[L * HID + j] + bhh[L * HID + j];

    // A-fragments: Wih (50x50) as 4 M-tiles x 2 K-tiles, f16; k>=50 zeroed
    h8 afr[4][2];
    {
        const float* Wp = WihR + (size_t)(L - 1) * HID * HID;
        const int r0 = lane & 15, kq = (lane >> 4) * 8;
#pragma unroll
        for (int m = 0; m < 4; m++) {
            int row = m * 16 + r0; if (row >= HID) row = 0;   // rows j>=50 unused
            const float* wr = Wp + row * HID;
#pragma unroll
            for (int kt = 0; kt < 2; kt++) {
                const int k0 = kt * 32 + kq;
#pragma unroll
                for (int i = 0; i < 8; i++)
                    afr[m][kt][i] = (k0 + i < HID) ? (_Float16)wr[k0 + i] : (_Float16)0.f;
            }
        }
    }

    float* prew = &pre_lds[L - 1][0][0];   // [GP][68] padded

    for (int s = 0; s < win; s += G) {
        wait_ge(&prog[L - 1], s + G);                        // hin rows s..s+G-1 ready
        if (s + G > RING) wait_ge(&prog[L + 1], s + G - RING);

        // ---- MFMA phase (prio 0): PRE cols [s, s+G) valid; rest garbage ----
        {
            const int tr = (s + (lane & 15)) & (RING - 1);
            const int kq = (lane >> 4) * 8;
            h8 b0 = *(const h8*)&ring[L - 1][tr][kq];        // k-tile 0
            h8 b1 = *(const h8*)&ring[L - 1][tr][32 + kq];   // k-tile 1 (k>=50: A=0)
#pragma unroll
            for (int m = 0; m < 4; m++) {
                f32x4 acc = {0.f, 0.f, 0.f, 0.f};
                acc = __builtin_amdgcn_mfma_f32_16x16x32_f16(afr[m][0], b0, acc, 0, 0, 0);
                acc = __builtin_amdgcn_mfma_f32_16x16x32_f16(afr[m][1], b1, acc, 0, 0, 0);
                float* pw = prew + (lane & 15) * 68 + m * 16 + (lane >> 4) * 4;
#pragma unroll
                for (int r = 0; r < 4; r++) pw[r] = acc[r];
            }
        }

        // ---- serial hse phase (prio 1: the recurrence critical chain) ----
        __builtin_amdgcn_s_setprio(1);
#pragma unroll
        for (int u = 0; u < G; u++) {
            const int t = s + u;
            h8 hse[7];
            load7(hse, &ring[L][(t - 1) & (RING - 1)][0]);
            const float pre = prew[u * 68 + lane];           // lane<50 meaningful
            float A = bias + pre, B = 0.f, C = 0.f, D = 0.f;
            dot28(hse, whhv, A, B, C, D);
            float h = fast_tanh((A + B) + (C + D));
            if (lane < HID) ring[L][t & (RING - 1)][lane] = (_Float16)h;
        }
        if (lane == 0)   // release INSIDE prio-1: consumer's critical path
            __hip_atomic_store(&prog[L], s + G, __ATOMIC_RELEASE, __HIP_MEMORY_SCOPE_WORKGROUP);
        __builtin_amdgcn_s_setprio(0);
    }
}

extern "C" __global__
__attribute__((amdgpu_flat_work_group_size(768, 768), amdgpu_waves_per_eu(3, 3)))
void rnn_fused(const float* __restrict__ x,     const float* __restrict__ Wih0,
               const float* __restrict__ WihR,  const float* __restrict__ Whh,
               const float* __restrict__ bih,   const float* __restrict__ bhh,
               const float* __restrict__ W1,    const float* __restrict__ b1,
               const float* __restrict__ W2,    const float* __restrict__ b2,
               float* __restrict__ out)
{
    __shared__ __align__(16) float    xsb[2][2 * XT * IN_DIM];           // 8 KB
    __shared__ __align__(16) _Float16 ring[2][NLAYERS][RING][RSH];       // 80 KB
    __shared__ __align__(16) float    pre_lds[2][NLAYERS - 1][GP][68];   // 34 KB
    __shared__ int prog[2][8];

    const int c    = blockIdx.x;
    const int tid  = threadIdx.x;
    const int w    = tid >> 6;
    const int lane = tid & 63;
    const int g    = (w >= 6) ? 1 : 0;   // chain index
    const int wg   = w - 6 * g;          // role within chain (0..5)

    const int base0 = c * (2 * CHUNK2);
    const int base1 = base0 + CHUNK2;
    const int T00   = (base0 - WARMUP > 0) ? (base0 - WARMUP) : 0;
    const int T01   = (base1 - WARMUP > 0) ? (base1 - WARMUP) : 0;
    const int win0  = base0 + CHUNK2 - T00;     // 256 (c=0) or 304; multiple of G
    const int win1  = base1 + CHUNK2 - T01;     // 304; multiple of G

    const int T0g  = g ? T01 : T00;
    const int wing = g ? win1 : win0;

    {   // zero ALL ring bytes: h_{-1}=0 AND k>=50 pads stay 0 forever
        int* rp = (int*)ring;
        const int n = (2 * NLAYERS * RING * RSH * 2) / 4;
        for (int i = tid; i < n; i += 768) rp[i] = 0;
    }
    if (tid < 16) ((int*)prog)[tid] = 0;
    __syncthreads();

    if (wg == 0) {
        // ================= layer 0 wave (per chain g) =================
        const int j = (lane < HID) ? lane : 0;
        v4f winv0, winv1;
        h2  whhv[28];
        winv0 = v4f{Wih0[j*IN_DIM+0], Wih0[j*IN_DIM+1], Wih0[j*IN_DIM+2], Wih0[j*IN_DIM+3]};
        winv1 = v4f{Wih0[j*IN_DIM+4], Wih0[j*IN_DIM+5], Wih0[j*IN_DIM+6], Wih0[j*IN_DIM+7]};
        loadw_h(Whh + j * HID, whhv);
        const float bias = bih[j] + bhh[j];

        const float* xg_base = x + (size_t)T0g * IN_DIM;
        const int nt = (wing + XT - 1) >> 6;    // last tile may be PARTIAL (wing=304)
        float4 pfa, pfb;
        {   // prime tile 0, register-prefetch tile 1 (always fully in-bounds)
            const float4* gp = (const float4*)xg_base;
            float4 a = gp[2 * lane], b = gp[2 * lane + 1];
            float4* d = (float4*)xsb[g];
            d[2 * lane] = a; d[2 * lane + 1] = b;
            const float4* g1 = (const float4*)(xg_base + (size_t)XT * IN_DIM);
            pfa = g1[2 * lane]; pfb = g1[2 * lane + 1];
        }

        for (int s = 0; s < wing; s += G) {
            if (s + G > RING) wait_ge(&prog[g][1], s + G - RING);
            if ((s & (XT - 1)) == 0 && s != 0) {                 // rotate x tile
                const int k = s >> 6;
                float4* d = (float4*)xsb[g] + (k & 1) * (XT * IN_DIM / 4);
                d[2 * lane] = pfa; d[2 * lane + 1] = pfb;
                if (k + 1 < nt) {
                    // OOB-safe tail prefetch (R18 lesson): clamp per-lane row.
                    size_t row = (size_t)T0g + (size_t)(k + 1) * XT + lane;
                    if (row >= SEQ_LEN) row = SEQ_LEN - 1;
                    const float4* gp = (const float4*)(x + row * IN_DIM);
                    pfa = gp[0]; pfb = gp[1];
                }
            }
            v4f xv[2];
            {
                const v4f* xp = (const v4f*)xsb[g] + ((s >> 6) & 1) * (XT * IN_DIM / 4) + (s & (XT - 1)) * 2;
                xv[0] = xp[0]; xv[1] = xp[1];
            }
            // ---- serial phase (prio 1: critical chain) ----
            __builtin_amdgcn_s_setprio(1);
#pragma unroll
            for (int u = 0; u < G; u++) {
                const int s2 = s + u;
                h8 hse[7];
                load7(hse, &ring[g][0][(s2 - 1) & (RING - 1)][0]);
                float A = bias, B = 0.f, C = 0.f, D = 0.f;
                A = __builtin_fmaf(xv[0].x, winv0.x, A);
                B = __builtin_fmaf(xv[0].y, winv0.y, B);
                C = __builtin_fmaf(xv[0].z, winv0.z, C);
                D = __builtin_fmaf(xv[0].w, winv0.w, D);
                A = __builtin_fmaf(xv[1].x, winv1.x, A);
                B = __builtin_fmaf(xv[1].y, winv1.y, B);
                C = __builtin_fmaf(xv[1].z, winv1.z, C);
                D = __builtin_fmaf(xv[1].w, winv1.w, D);
                dot28(hse, whhv, A, B, C, D);
                float h = fast_tanh((A + B) + (C + D));
                if (lane < HID) ring[g][0][s2 & (RING - 1)][lane] = (_Float16)h;
                if (u < G - 1) {
                    const int s3 = s2 + 1;
                    const v4f* xp = (const v4f*)xsb[g] + ((s3 >> 6) & 1) * (XT * IN_DIM / 4) + (s3 & (XT - 1)) * 2;
                    xv[0] = xp[0]; xv[1] = xp[1];
                }
            }
            if (lane == 0)   // release inside prio-1 (consumer critical path)
                __hip_atomic_store(&prog[g][0], s + G, __ATOMIC_RELEASE, __HIP_MEMORY_SCOPE_WORKGROUP);
            __builtin_amdgcn_s_setprio(0);
        }
    } else if (wg <= 4) {
        layer_mfma(ring[g], pre_lds[g], prog[g], wg, WihR, Whh, bih, bhh, lane, wing);
    } else {
        // ================= head wave (per chain g, prio 0: off critical path) =================
        const int j = (lane < 20) ? lane : 0;
        h2 w1v[28];
        loadw_h(W1 + j * HID, w1v);
        const float b1_w = b1[j];
        const float w2_w = W2[j];
        const float b2_w = b2[0];

        const int warm = wing - CHUNK2;   // 48 or 0: multiple of G
        if (lane == 0)   // pre-publish warmup region: layer 4 never stalls there
            __hip_atomic_store(&prog[g][5], warm, __ATOMIC_RELEASE, __HIP_MEMORY_SCOPE_WORKGROUP);

        for (int s = warm; s < wing; s += G) {
            wait_ge(&prog[g][4], s + G);
            h8 h4[7];
            load7(h4, &ring[g][4][s & (RING - 1)][0]);
#pragma unroll
            for (int u = 0; u < G; u++) {
                const int s2 = s + u;
                const int t = T0g + s2;
                float A = b1_w, B = 0.f, C = 0.f, D = 0.f;
                dot28(h4, w1v, A, B, C, D);
                float z = (A + B) + (C + D);
                z = fmaxf(z, 0.f);
                float zz = (lane < 20) ? z * w2_w : 0.f;
                if (u < G - 1) load7(h4, &ring[g][4][(s2 + 1) & (RING - 1)][0]);
#pragma unroll
                for (int off = 32; off > 0; off >>= 1) zz += __shfl_down(zz, off, 64);
                if (lane == 0) out[t] = fast_sigmoid(zz + b2_w);
            }
            if (lane == 0)
                __hip_atomic_store(&prog[g][5], s + G, __ATOMIC_RELEASE, __HIP_MEMORY_SCOPE_WORKGROUP);
        }
    }
}

extern "C" void kernel_launch(void* const* d_in, const int* in_sizes, int n_in,
                              void* d_out, int out_size, void* d_ws, size_t ws_size,
                              hipStream_t stream) {
    (void)in_sizes; (void)n_in; (void)d_ws; (void)ws_size; (void)out_size;
    rnn_fused<<<NBLOCKS, 768, 0, stream>>>(
        (const float*)d_in[0], (const float*)d_in[1], (const float*)d_in[2],
        (const float*)d_in[3], (const float*)d_in[4], (const float*)d_in[5],
        (const float*)d_in[6], (const float*)d_in[7], (const float*)d_in[8],
        (const float*)d_in[9], (float*)d_out);
}

// Round 26
// 214.497 us; speedup vs baseline: 1.0511x; 1.0511x over previous
//
#include <hip/hip_runtime.h>
#include <stdint.h>

#define SEQ_LEN 131072
#define IN_DIM  8
#define HID     50
#define NLAYERS 5
#define CHUNK2  256                  // outputs per CHAIN; 2 chains per block (waves 0-5 / 6-11)
#define WARMUP  48                   // locked (R22)
#define NBLOCKS (SEQ_LEN / (2 * CHUNK2))  // 256 blocks == 256 CUs
#define RING    64
#define RSH     64                   // halves per ring row: 128B; k=50..63 stay ZERO (MFMA K-pad)
#define XT      64                   // x-tile steps (double buffered); win=304 -> partial last tile
#define G       8                    // R26: revert to G=8 (optimum: 16->162, 8->160, 4->170 us)
#define GP      16                   // PRE buffer rows == MFMA N-tile

typedef float    v4f   __attribute__((ext_vector_type(4)));
typedef float    f32x4 __attribute__((ext_vector_type(4)));
typedef _Float16 h2    __attribute__((ext_vector_type(2)));
typedef _Float16 h8    __attribute__((ext_vector_type(8)));

#if __has_builtin(__builtin_amdgcn_fdot2)
#define FDOT2(a, b, c) __builtin_amdgcn_fdot2((a), (b), (c), false)
#else
#define FDOT2(a, b, c) __builtin_fmaf((float)(a).x, (float)(b).x, \
                        __builtin_fmaf((float)(a).y, (float)(b).y, (c)))
#endif

__device__ __forceinline__ float fast_tanh(float x) {
    float e = __expf(2.0f * x);
    return 1.0f - 2.0f * __builtin_amdgcn_rcpf(1.0f + e);
}
__device__ __forceinline__ float fast_sigmoid(float x) {
    float e = __expf(-x);
    return __builtin_amdgcn_rcpf(1.0f + e);
}
__device__ __forceinline__ void wait_ge(volatile int* p, int target) {
    while (__hip_atomic_load((int*)p, __ATOMIC_ACQUIRE, __HIP_MEMORY_SCOPE_WORKGROUP) < target) {}
}
// 7 x ds_read_b128 wave-uniform broadcast of one f16 h-row (112B used of 128B)
__device__ __forceinline__ void load7(h8* v, const _Float16* p) {
    const h8* p8 = (const h8*)p;
#pragma unroll
    for (int q = 0; q < 7; q++) v[q] = p8[q];
}
// 50 f32 weights -> 28 h2 (f16), zero-padded
__device__ __forceinline__ void loadw_h(const float* wp, h2* v) {
#pragma unroll
    for (int i = 0; i < 25; i++)
        v[i] = h2{(_Float16)wp[2*i], (_Float16)wp[2*i+1]};
    v[25] = h2{(_Float16)0.f, (_Float16)0.f};
    v[26] = h2{(_Float16)0.f, (_Float16)0.f};
    v[27] = h2{(_Float16)0.f, (_Float16)0.f};
}
// acc += a(56 halves) . w(28 h2), f32 accumulate via v_dot2_f32_f16, 4 chains
__device__ __forceinline__ void dot28(const h8* a, const h2* w,
                                      float& A, float& B, float& C, float& D) {
#pragma unroll
    for (int q = 0; q < 7; q++) {
        A = FDOT2(__builtin_shufflevector(a[q], a[q], 0, 1), w[4*q+0], A);
        B = FDOT2(__builtin_shufflevector(a[q], a[q], 2, 3), w[4*q+1], B);
        C = FDOT2(__builtin_shufflevector(a[q], a[q], 4, 5), w[4*q+2], C);
        D = FDOT2(__builtin_shufflevector(a[q], a[q], 6, 7), w[4*q+3], D);
    }
}

// Layers 1..4 (runtime L: one I-stream shared by 8 waves across both chains).
// hin contribution = bulk MFMA GEMM, 16-col tile, only cols [0,G) consumed.
// hse recurrence serial in LDS at prio 1 (T5); release store INSIDE the prio-1
// region (R26 single-variable test: consumer's critical path).
__device__ void layer_mfma(
    _Float16 (&ring)[NLAYERS][RING][RSH],
    float (&pre_lds)[NLAYERS - 1][GP][68],
    int* prog, const int L,
    const float* __restrict__ WihR, const float* __restrict__ Whh,
    const float* __restrict__ bih,  const float* __restrict__ bhh,
    const int lane, const int win)
{
    const int j = (lane < HID) ? lane : 0;
    h2 whhv[28];
    loadw_h(Whh + (size_t)L * HID * HID + j * HID, whhv);
    const float bias = bih[L * HID + j] + bhh[L * HID + j];

    // A-fragments: Wih (50x50) as 4 M-tiles x 2 K-tiles, f16; k>=50 zeroed
    h8 afr[4][2];
    {
        const float* Wp = WihR + (size_t)(L - 1) * HID * HID;
        const int r0 = lane & 15, kq = (lane >> 4) * 8;
#pragma unroll
        for (int m = 0; m < 4; m++) {
            int row = m * 16 + r0; if (row >= HID) row = 0;   // rows j>=50 unused
            const float* wr = Wp + row * HID;
#pragma unroll
            for (int kt = 0; kt < 2; kt++) {
                const int k0 = kt * 32 + kq;
#pragma unroll
                for (int i = 0; i < 8; i++)
                    afr[m][kt][i] = (k0 + i < HID) ? (_Float16)wr[k0 + i] : (_Float16)0.f;
            }
        }
    }

    float* prew = &pre_lds[L - 1][0][0];   // [GP][68] padded

    for (int s = 0; s < win; s += G) {
        wait_ge(&prog[L - 1], s + G);                        // hin rows s..s+G-1 ready
        if (s + G > RING) wait_ge(&prog[L + 1], s + G - RING);

        // ---- MFMA phase (prio 0): PRE cols [s, s+G) valid; rest garbage ----
        {
            const int tr = (s + (lane & 15)) & (RING - 1);
            const int kq = (lane >> 4) * 8;
            h8 b0 = *(const h8*)&ring[L - 1][tr][kq];        // k-tile 0
            h8 b1 = *(const h8*)&ring[L - 1][tr][32 + kq];   // k-tile 1 (k>=50: A=0)
#pragma unroll
            for (int m = 0; m < 4; m++) {
                f32x4 acc = {0.f, 0.f, 0.f, 0.f};
                acc = __builtin_amdgcn_mfma_f32_16x16x32_f16(afr[m][0], b0, acc, 0, 0, 0);
                acc = __builtin_amdgcn_mfma_f32_16x16x32_f16(afr[m][1], b1, acc, 0, 0, 0);
                float* pw = prew + (lane & 15) * 68 + m * 16 + (lane >> 4) * 4;
#pragma unroll
                for (int r = 0; r < 4; r++) pw[r] = acc[r];
            }
        }

        // ---- serial hse phase (prio 1: the recurrence critical chain) ----
        __builtin_amdgcn_s_setprio(1);
#pragma unroll
        for (int u = 0; u < G; u++) {
            const int t = s + u;
            h8 hse[7];
            load7(hse, &ring[L][(t - 1) & (RING - 1)][0]);
            const float pre = prew[u * 68 + lane];           // lane<50 meaningful
            float A = bias + pre, B = 0.f, C = 0.f, D = 0.f;
            dot28(hse, whhv, A, B, C, D);
            float h = fast_tanh((A + B) + (C + D));
            if (lane < HID) ring[L][t & (RING - 1)][lane] = (_Float16)h;
        }
        if (lane == 0)   // release INSIDE prio-1: consumer's critical path
            __hip_atomic_store(&prog[L], s + G, __ATOMIC_RELEASE, __HIP_MEMORY_SCOPE_WORKGROUP);
        __builtin_amdgcn_s_setprio(0);
    }
}

extern "C" __global__
__attribute__((amdgpu_flat_work_group_size(768, 768), amdgpu_waves_per_eu(3, 3)))
void rnn_fused(const float* __restrict__ x,     const float* __restrict__ Wih0,
               const float* __restrict__ WihR,  const float* __restrict__ Whh,
               const float* __restrict__ bih,   const float* __restrict__ bhh,
               const float* __restrict__ W1,    const float* __restrict__ b1,
               const float* __restrict__ W2,    const float* __restrict__ b2,
               float* __restrict__ out)
{
    __shared__ __align__(16) float    xsb[2][2 * XT * IN_DIM];           // 8 KB
    __shared__ __align__(16) _Float16 ring[2][NLAYERS][RING][RSH];       // 80 KB
    __shared__ __align__(16) float    pre_lds[2][NLAYERS - 1][GP][68];   // 34 KB
    __shared__ int prog[2][8];

    const int c    = blockIdx.x;
    const int tid  = threadIdx.x;
    const int w    = tid >> 6;
    const int lane = tid & 63;
    const int g    = (w >= 6) ? 1 : 0;   // chain index
    const int wg   = w - 6 * g;          // role within chain (0..5)

    const int base0 = c * (2 * CHUNK2);
    const int base1 = base0 + CHUNK2;
    const int T00   = (base0 - WARMUP > 0) ? (base0 - WARMUP) : 0;
    const int T01   = (base1 - WARMUP > 0) ? (base1 - WARMUP) : 0;
    const int win0  = base0 + CHUNK2 - T00;     // 256 (c=0) or 304; multiple of G
    const int win1  = base1 + CHUNK2 - T01;     // 304; multiple of G

    const int T0g  = g ? T01 : T00;
    const int wing = g ? win1 : win0;

    {   // zero ALL ring bytes: h_{-1}=0 AND k>=50 pads stay 0 forever
        int* rp = (int*)ring;
        const int n = (2 * NLAYERS * RING * RSH * 2) / 4;
        for (int i = tid; i < n; i += 768) rp[i] = 0;
    }
    if (tid < 16) ((int*)prog)[tid] = 0;
    __syncthreads();

    if (wg == 0) {
        // ================= layer 0 wave (per chain g) =================
        const int j = (lane < HID) ? lane : 0;
        v4f winv0, winv1;
        h2  whhv[28];
        winv0 = v4f{Wih0[j*IN_DIM+0], Wih0[j*IN_DIM+1], Wih0[j*IN_DIM+2], Wih0[j*IN_DIM+3]};
        winv1 = v4f{Wih0[j*IN_DIM+4], Wih0[j*IN_DIM+5], Wih0[j*IN_DIM+6], Wih0[j*IN_DIM+7]};
        loadw_h(Whh + j * HID, whhv);
        const float bias = bih[j] + bhh[j];

        const float* xg_base = x + (size_t)T0g * IN_DIM;
        const int nt = (wing + XT - 1) >> 6;    // last tile may be PARTIAL (wing=304)
        float4 pfa, pfb;
        {   // prime tile 0, register-prefetch tile 1 (always fully in-bounds)
            const float4* gp = (const float4*)xg_base;
            float4 a = gp[2 * lane], b = gp[2 * lane + 1];
            float4* d = (float4*)xsb[g];
            d[2 * lane] = a; d[2 * lane + 1] = b;
            const float4* g1 = (const float4*)(xg_base + (size_t)XT * IN_DIM);
            pfa = g1[2 * lane]; pfb = g1[2 * lane + 1];
        }

        for (int s = 0; s < wing; s += G) {
            if (s + G > RING) wait_ge(&prog[g][1], s + G - RING);
            if ((s & (XT - 1)) == 0 && s != 0) {                 // rotate x tile
                const int k = s >> 6;
                float4* d = (float4*)xsb[g] + (k & 1) * (XT * IN_DIM / 4);
                d[2 * lane] = pfa; d[2 * lane + 1] = pfb;
                if (k + 1 < nt) {
                    // OOB-safe tail prefetch (R18 lesson): clamp per-lane row.
                    size_t row = (size_t)T0g + (size_t)(k + 1) * XT + lane;
                    if (row >= SEQ_LEN) row = SEQ_LEN - 1;
                    const float4* gp = (const float4*)(x + row * IN_DIM);
                    pfa = gp[0]; pfb = gp[1];
                }
            }
            v4f xv[2];
            {
                const v4f* xp = (const v4f*)xsb[g] + ((s >> 6) & 1) * (XT * IN_DIM / 4) + (s & (XT - 1)) * 2;
                xv[0] = xp[0]; xv[1] = xp[1];
            }
            // ---- serial phase (prio 1: critical chain) ----
            __builtin_amdgcn_s_setprio(1);
#pragma unroll
            for (int u = 0; u < G; u++) {
                const int s2 = s + u;
                h8 hse[7];
                load7(hse, &ring[g][0][(s2 - 1) & (RING - 1)][0]);
                float A = bias, B = 0.f, C = 0.f, D = 0.f;
                A = __builtin_fmaf(xv[0].x, winv0.x, A);
                B = __builtin_fmaf(xv[0].y, winv0.y, B);
                C = __builtin_fmaf(xv[0].z, winv0.z, C);
                D = __builtin_fmaf(xv[0].w, winv0.w, D);
                A = __builtin_fmaf(xv[1].x, winv1.x, A);
                B = __builtin_fmaf(xv[1].y, winv1.y, B);
                C = __builtin_fmaf(xv[1].z, winv1.z, C);
                D = __builtin_fmaf(xv[1].w, winv1.w, D);
                dot28(hse, whhv, A, B, C, D);
                float h = fast_tanh((A + B) + (C + D));
                if (lane < HID) ring[g][0][s2 & (RING - 1)][lane] = (_Float16)h;
                if (u < G - 1) {
                    const int s3 = s2 + 1;
                    const v4f* xp = (const v4f*)xsb[g] + ((s3 >> 6) & 1) * (XT * IN_DIM / 4) + (s3 & (XT - 1)) * 2;
                    xv[0] = xp[0]; xv[1] = xp[1];
                }
            }
            if (lane == 0)   // release inside prio-1 (consumer critical path)
                __hip_atomic_store(&prog[g][0], s + G, __ATOMIC_RELEASE, __HIP_MEMORY_SCOPE_WORKGROUP);
            __builtin_amdgcn_s_setprio(0);
        }
    } else if (wg <= 4) {
        layer_mfma(ring[g], pre_lds[g], prog[g], wg, WihR, Whh, bih, bhh, lane, wing);
    } else {
        // ================= head wave (per chain g, prio 0: off critical path) =================
        const int j = (lane < 20) ? lane : 0;
        h2 w1v[28];
        loadw_h(W1 + j * HID, w1v);
        const float b1_w = b1[j];
        const float w2_w = W2[j];
        const float b2_w = b2[0];

        const int warm = wing - CHUNK2;   // 48 or 0: multiple of G
        if (lane == 0)   // pre-publish warmup region: layer 4 never stalls there
            __hip_atomic_store(&prog[g][5], warm, __ATOMIC_RELEASE, __HIP_MEMORY_SCOPE_WORKGROUP);

        for (int s = warm; s < wing; s += G) {
            wait_ge(&prog[g][4], s + G);
            h8 h4[7];
            load7(h4, &ring[g][4][s & (RING - 1)][0]);
#pragma unroll
            for (int u = 0; u < G; u++) {
                const int s2 = s + u;
                const int t = T0g + s2;
                float A = b1_w, B = 0.f, C = 0.f, D = 0.f;
                dot28(h4, w1v, A, B, C, D);
                float z = (A + B) + (C + D);
                z = fmaxf(z, 0.f);
                float zz = (lane < 20) ? z * w2_w : 0.f;
                if (u < G - 1) load7(h4, &ring[g][4][(s2 + 1) & (RING - 1)][0]);
#pragma unroll
                for (int off = 32; off > 0; off >>= 1) zz += __shfl_down(zz, off, 64);
                if (lane == 0) out[t] = fast_sigmoid(zz + b2_w);
            }
            if (lane == 0)
                __hip_atomic_store(&prog[g][5], s + G, __ATOMIC_RELEASE, __HIP_MEMORY_SCOPE_WORKGROUP);
        }
    }
}

extern "C" void kernel_launch(void* const* d_in, const int* in_sizes, int n_in,
                              void* d_out, int out_size, void* d_ws, size_t ws_size,
                              hipStream_t stream) {
    (void)in_sizes; (void)n_in; (void)d_ws; (void)ws_size; (void)out_size;
    rnn_fused<<<NBLOCKS, 768, 0, stream>>>(
        (const float*)d_in[0], (const float*)d_in[1], (const float*)d_in[2],
        (const float*)d_in[3], (const float*)d_in[4], (const float*)d_in[5],
        (const float*)d_in[6], (const float*)d_in[7], (const float*)d_in[8],
        (const float*)d_in[9], (float*)d_out);
}